// Round 8
// baseline (1057.716 us; speedup 1.0000x reference)
//
#include <hip/hip_runtime.h>
#include <cstdint>

#define NXI  2048
#define LLEN 2048
#define NN   1024
#define MM   1024
#define SS   6144
#define EPSV 0.001f
#define NCHEB 12

typedef __attribute__((ext_vector_type(8))) __bf16 bf16x8;
typedef __attribute__((ext_vector_type(4))) float  f32x4;
typedef __attribute__((ext_vector_type(8))) unsigned short us8;
typedef unsigned short ushort_t;

struct Coefs { float g1[NCHEB]; float g2[NCHEB]; };

// ---------- helpers ----------
__device__ __forceinline__ unsigned short f2bf(float f) {
  unsigned u = __float_as_uint(f);
  unsigned r = (u + 0x7FFFu + ((u >> 16) & 1u)) >> 16;   // RNE
  return (unsigned short)r;
}

__device__ __forceinline__ void gld16(const void* g, void* l) {
  __builtin_amdgcn_global_load_lds((const __attribute__((address_space(1))) void*)g,
                                   (__attribute__((address_space(3))) void*)l,
                                   16, 0, 0);
}

__device__ __forceinline__ void gatomic_addf(float* p, float v) {
  asm volatile("global_atomic_add_f32 %0, %1, off" :: "v"(p), "v"(v) : "memory");
}

__device__ __forceinline__ void gridbar(unsigned* cnt, unsigned target) {
  __threadfence();
  __syncthreads();
  if (threadIdx.x == 0) {
    __hip_atomic_fetch_add(cnt, 1u, __ATOMIC_ACQ_REL, __HIP_MEMORY_SCOPE_AGENT);
    while (__hip_atomic_load(cnt, __ATOMIC_ACQUIRE, __HIP_MEMORY_SCOPE_AGENT) < target)
      __builtin_amdgcn_s_sleep(8);
  }
  __syncthreads();
}

// ---------- 1) transpose + f32->bf16: XT[i][k] = bf16(X[k][i]) ----------
__global__ __launch_bounds__(256) void k_transpose(const float* __restrict__ X,
                                                   ushort_t* __restrict__ XT) {
  __shared__ float tile[64][65];
  const int bx = blockIdx.x, by = blockIdx.y;
  const int t = threadIdx.x;
  const int r = t >> 2, c0 = (t & 3) << 4;
  const float* src = X + (size_t)(by * 64 + r) * SS + bx * 64 + c0;
#pragma unroll
  for (int s = 0; s < 16; s += 4) {
    const float4 v = *(const float4*)(src + s);
    tile[r][c0 + s]     = v.x;
    tile[r][c0 + s + 1] = v.y;
    tile[r][c0 + s + 2] = v.z;
    tile[r][c0 + s + 3] = v.w;
  }
  __syncthreads();
  ushort_t* dst = XT + (size_t)(bx * 64 + r) * SS + by * 64 + c0;
  us8 o0, o1;
#pragma unroll
  for (int s = 0; s < 8; ++s) o0[s] = f2bf(tile[c0 + s][r]);
#pragma unroll
  for (int s = 0; s < 8; ++s) o1[s] = f2bf(tile[c0 + 8 + s][r]);
  *(us8*)dst = o0;
  *(us8*)(dst + 8) = o1;
}

// ---------- 2) SYRK: 300 lower/full tiles; bids 0..255 big (full K), 256..431 = 44 tail
// tiles K-split x4 with atomic-add epilogue onto zeroed region. ----------
__global__ __launch_bounds__(512) void k_syrk(const ushort_t* __restrict__ XT,
                                              float* __restrict__ Hws) {
  const int bid = blockIdx.x;
  int u, kq4;
  if (bid < 256) { u = (bid & 7) * 32 + (bid >> 3); kq4 = -1; }
  else { const int s = bid - 256; u = 256 + (s >> 2); kq4 = s & 3; }
  int z, bm, bn;
  {
    int base;
    if      (u < 36)  { z = 0; base = 0; }
    else if (u < 100) { z = 1; base = 36; }
    else if (u < 136) { z = 2; base = 100; }
    else if (u < 200) { z = 3; base = 136; }
    else if (u < 264) { z = 4; base = 200; }
    else              { z = 5; base = 264; }
    const int k = u - base;
    if (z == 1 || z == 3 || z == 4) { bm = k >> 3; bn = k & 7; }
    else { int r = 0; while ((r + 1) * (r + 2) / 2 <= k) ++r; bm = r; bn = k - r * (r + 1) / 2; }
  }
  const int Rb = (z >= 3) ? 2 : ((z >= 1) ? 1 : 0);
  const int Cb = z - (Rb * (Rb + 1)) / 2;
  float* __restrict__ Hout = Hws + (size_t)z * (2048ull * 2048ull);

  const int c = threadIdx.x;
  const int lane = c & 63, wave = c >> 6;
  const int wm = wave >> 2, wn = wave & 3;
  const int rl = lane & 15, kq = lane >> 4;

  __shared__ ushort_t lds[65536];        // 128 KiB
  ushort_t* A_lds = lds;
  ushort_t* B_lds = lds + 32768;

  const size_t arow0 = (size_t)Rb * 2048 + (size_t)bm * 256;
  const size_t brow0 = (size_t)Cb * 2048 + (size_t)bn * 256;
  const ushort_t* Arows = XT + arow0 * SS;
  const ushort_t* Brows = XT + brow0 * SS;

  const int t0 = (kq4 < 0) ? 0 : kq4 * 24;
  const int t1 = (kq4 < 0) ? 96 : t0 + 24;

#define STAGE_UNIT(ROWS, KELEM, UNITPTR)                                      \
  {                                                                           \
    _Pragma("unroll")                                                         \
    for (int q = 0; q < 2; ++q) {                                             \
      const int p  = q * 512 + c;                                             \
      const int r_ = p >> 2, chp_ = p & 3;                                    \
      const int chl_ = chp_ ^ ((r_ >> 1) & 3);                                \
      gld16((ROWS) + (size_t)r_ * SS + (KELEM) + chl_ * 8, (UNITPTR) + p * 8);\
    }                                                                         \
  }

#define LD_A(AU, MG, AARR)                                                    \
  {                                                                           \
    _Pragma("unroll")                                                         \
    for (int m4 = 0; m4 < 4; ++m4) {                                          \
      const int row_ = wm * 128 + ((MG) * 4 + m4) * 16 + rl;                  \
      const int chp_ = kq ^ ((row_ >> 1) & 3);                                \
      AARR[m4] = *(const bf16x8*)((AU) + row_ * 32 + chp_ * 8);               \
    }                                                                         \
  }

#define LD_B(BU, BARR)                                                        \
  {                                                                           \
    _Pragma("unroll")                                                         \
    for (int nf = 0; nf < 4; ++nf) {                                          \
      const int row_ = wn * 64 + nf * 16 + rl;                                \
      const int chp_ = kq ^ ((row_ >> 1) & 3);                                \
      BARR[nf] = *(const bf16x8*)((BU) + row_ * 32 + chp_ * 8);               \
    }                                                                         \
  }

#define DO_MFMA(MG, AARR, BARR)                                               \
  {                                                                           \
    __builtin_amdgcn_s_setprio(1);                                            \
    _Pragma("unroll")                                                         \
    for (int m4 = 0; m4 < 4; ++m4)                                            \
      _Pragma("unroll")                                                       \
      for (int nf = 0; nf < 4; ++nf)                                          \
        acc[(MG) * 4 + m4][nf] = __builtin_amdgcn_mfma_f32_16x16x32_bf16(     \
            AARR[m4], BARR[nf], acc[(MG) * 4 + m4][nf], 0, 0, 0);             \
    __builtin_amdgcn_s_setprio(0);                                            \
  }

  // prologue: kh0(t0), kh1(t0), kh0(t0+1)  -> 12 loads/thread in flight
  STAGE_UNIT(Arows, t0 * 64,      A_lds + 0 * 8192);
  STAGE_UNIT(Brows, t0 * 64,      B_lds + 0 * 8192);
  STAGE_UNIT(Arows, t0 * 64 + 32, A_lds + 1 * 8192);
  STAGE_UNIT(Brows, t0 * 64 + 32, B_lds + 1 * 8192);
  STAGE_UNIT(Arows, t0 * 64 + 64, A_lds + 2 * 8192);
  STAGE_UNIT(Brows, t0 * 64 + 64, B_lds + 2 * 8192);

  f32x4 acc[8][4] = {};

  for (int t = t0; t < t1; ++t) {
    const int db = t & 1;                // t0 even -> parity consistent
    const ushort_t* Au0 = A_lds + (db * 2 + 0) * 8192;
    const ushort_t* Bu0 = B_lds + (db * 2 + 0) * 8192;
    const ushort_t* Au1 = A_lds + (db * 2 + 1) * 8192;
    const ushort_t* Bu1 = B_lds + (db * 2 + 1) * 8192;
    ushort_t* An1 = A_lds + (((db ^ 1) * 2) + 1) * 8192;   // kh1(t+1)
    ushort_t* Bn1 = B_lds + (((db ^ 1) * 2) + 1) * 8192;
    ushort_t* An0 = A_lds + (db * 2 + 0) * 8192;           // kh0(t+2)
    ushort_t* Bn0 = B_lds + (db * 2 + 0) * 8192;

    if (t < t1 - 1) { asm volatile("s_waitcnt vmcnt(8)" ::: "memory"); }
    else            { asm volatile("s_waitcnt vmcnt(4)" ::: "memory"); }
    __builtin_amdgcn_s_barrier();

    bf16x8 aA[4], bB[4];
    LD_A(Au0, 0, aA); LD_B(Bu0, bB);
    if (t < t1 - 1) { STAGE_UNIT(Arows, (t + 1) * 64 + 32, An1);
                      STAGE_UNIT(Brows, (t + 1) * 64 + 32, Bn1); }
    DO_MFMA(0, aA, bB);
    LD_A(Au0, 1, aA);
    DO_MFMA(1, aA, bB);

    if (t < t1 - 1) { asm volatile("s_waitcnt vmcnt(8)" ::: "memory"); }
    else            { asm volatile("s_waitcnt vmcnt(0)" ::: "memory"); }
    __builtin_amdgcn_s_barrier();

    LD_A(Au1, 0, aA); LD_B(Bu1, bB);
    if (t < t1 - 2) { STAGE_UNIT(Arows, (t + 2) * 64, An0);
                      STAGE_UNIT(Brows, (t + 2) * 64, Bn0); }
    DO_MFMA(0, aA, bB);
    LD_A(Au1, 1, aA);
    DO_MFMA(1, aA, bB);
  }

  const int cr = kq << 2, cc = rl;
  const bool dg = (Rb == Cb);
  const bool addeps = (kq4 <= 0);        // big mode or K-quarter 0
#pragma unroll
  for (int mf = 0; mf < 8; ++mf) {
#pragma unroll
    for (int nf = 0; nf < 4; ++nf) {
#pragma unroll
      for (int v = 0; v < 4; ++v) {
        const int row = bm * 256 + wm * 128 + mf * 16 + cr + v;
        const int col = bn * 256 + wn * 64 + nf * 16 + cc;
        float val = acc[mf][nf][v];
        if (dg && row == col && addeps) val += EPSV;
        float* p = Hout + (size_t)row * 2048 + col;
        if (kq4 < 0) *p = val;
        else         gatomic_addf(p, val);
      }
    }
  }
#undef STAGE_UNIT
#undef LD_A
#undef LD_B
#undef DO_MFMA
}

// ---------- 3) fused: E-combine w/ symmetric mirror (0..1023) | invLam (1024..1031) | base (1032..1159)
// E written to Enew (NOT in place: mirror reads cross tiles). ----------
__global__ __launch_bounds__(256) void k_mid(const float* __restrict__ H0,
                                             const float* __restrict__ H5,
                                             const float* __restrict__ Y,
                                             float* __restrict__ Enew,
                                             const float* __restrict__ H22,
                                             float* __restrict__ invLam,
                                             const float* __restrict__ H21,
                                             const float* __restrict__ D12,
                                             const float* __restrict__ xi,
                                             const float* __restrict__ w,
                                             float* __restrict__ bacc) {
  const int bid = blockIdx.x, t = threadIdx.x;
  if (bid < 1024) {
    __shared__ float yt[64][65];
    __shared__ float hs[64][65];
    const int bx = bid & 31, by = bid >> 5;
    const int a64 = (by > bx) ? by : bx;
    const int b64 = (by > bx) ? bx : by;
    const int r = t >> 2, c0 = (t & 3) << 4;
    const float* ys  = Y  + (size_t)(bx * 64 + r) * 2048 + by * 64 + c0;
    const float* h0s = H0 + (size_t)(a64 * 64 + r) * 2048 + b64 * 64 + c0;
    const float* h5s = H5 + (size_t)(a64 * 64 + r) * 2048 + b64 * 64 + c0;
#pragma unroll
    for (int s = 0; s < 16; s += 4) {
      const float4 v  = *(const float4*)(ys + s);
      const float4 ha = *(const float4*)(h0s + s);
      const float4 hb = *(const float4*)(h5s + s);
      yt[r][c0 + s]     = v.x;  yt[r][c0 + s + 1] = v.y;
      yt[r][c0 + s + 2] = v.z;  yt[r][c0 + s + 3] = v.w;
      hs[r][c0 + s]     = ha.x + hb.x;  hs[r][c0 + s + 1] = ha.y + hb.y;
      hs[r][c0 + s + 2] = ha.z + hb.z;  hs[r][c0 + s + 3] = ha.w + hb.w;
    }
    __syncthreads();
    const size_t obase = (size_t)(by * 64 + r) * 2048 + bx * 64 + c0;
    const float* yd = Y + obase;
    float* eo = Enew + obase;
#pragma unroll
    for (int s4 = 0; s4 < 16; s4 += 4) {
      const float4 y = *(const float4*)(yd + s4);
      float4 e;
      float yv[4] = {y.x, y.y, y.z, y.w};
      float ev[4];
#pragma unroll
      for (int q = 0; q < 4; ++q) {
        const int j = c0 + s4 + q;
        float hsel;
        if (by > bx)      hsel = hs[r][j];
        else if (by < bx) hsel = hs[j][r];
        else              hsel = (r >= j) ? hs[r][j] : hs[j][r];
        ev[q] = 0.5f * (hsel + yv[q] - yt[j][r]);
      }
      e.x = ev[0]; e.y = ev[1]; e.z = ev[2]; e.w = ev[3];
      *(float4*)(eo + s4) = e;
    }
  } else if (bid < 1032) {
    const int i = (bid - 1024) * 256 + t;
    // exponent scale for tanh via 2^x: 4*log2(e)/H22[i][i]
    invLam[i] = 5.770780163555854f / H22[(size_t)i * 2048 + i];
  } else {
    const int lane = t & 63;
    const int wv = (bid - 1032) * 4 + (t >> 6);
    for (int row = wv; row < LLEN; row += 512) {
      const float* hr = H21 + (size_t)row * NXI;
      float s = 0.f;
      for (int k0 = 0; k0 < NXI; k0 += 256) {
        const int li = k0 + lane * 4;
        const float4 h = *(const float4*)(hr + li);
        const float4 x4 = *(const float4*)(xi + li);
        s += h.x * x4.x + h.y * x4.y + h.z * x4.z + h.w * x4.w;
      }
      const float* dr = D12 + (size_t)row * NN;
      float s2 = 0.f;
      for (int k0 = 0; k0 < NN; k0 += 256) {
        const int li = k0 + lane * 4;
        const float4 h = *(const float4*)(dr + li);
        const float4 x4 = *(const float4*)(w + li);
        s2 += h.x * x4.x + h.y * x4.y + h.z * x4.z + h.w * x4.w;
      }
      float tot = s2 - s;
#pragma unroll
      for (int off = 32; off > 0; off >>= 1) tot += __shfl_xor(tot, off, 64);
      if (lane == 0) bacc[row] = tot;
    }
  }
}

// ---------- 4) eps solve, lookahead L=3: producer applies j=b-3..b-1 itself
// (tiles prefetched into LDS by waves1-3 during prior serial chain; eps ring in LDS);
// consumers cover j<=b-4. flags[0]=pub count; flags[64+r*16]=consumer r done ----------
__global__ __launch_bounds__(256) void k_eps(const float* __restrict__ H22,
                                             const float* __restrict__ bacc,
                                             const float* __restrict__ invLam,
                                             float* __restrict__ eps_g,
                                             float* __restrict__ accfin,
                                             unsigned* __restrict__ flags) {
  const int g = blockIdx.x, t = threadIdx.x;
  if (g == 0) {
    __shared__ float diagL[2][64 * 65];
    __shared__ float chunkL[2][3][64 * 68];
    __shared__ float epsR[4][64];
    __shared__ float redL[256];
    // prologue: diag(0)
    for (int idx = t; idx < 1024; idx += 256) {
      const int row = idx >> 4, c4 = (idx & 15) * 4;
      *(float4*)&diagL[0][row * 65 + c4] =
          *(const float4*)(H22 + (size_t)row * 2048 + c4);
    }
    __syncthreads();
    for (int b = 0; b < 32; ++b) {
      const int cur = b & 1, nxt = cur ^ 1;
      if (b > 0) {
        while (__hip_atomic_load(&flags[64 + b * 16], __ATOMIC_ACQUIRE,
                                 __HIP_MEMORY_SCOPE_AGENT) == 0u)
          __builtin_amdgcn_s_sleep(1);
      }
      // apply producer-side chunks j = b-3..b-1
      {
        const int row = t >> 2, q = t & 3;
        float part = 0.f;
#pragma unroll
        for (int sl = 0; sl < 3; ++sl) {
          const int j = b - 3 + sl;
          if (j >= 0) {
            const float* ch = &chunkL[cur][sl][row * 68 + q * 16];
            const float* ep = &epsR[j & 3][q * 16];
#pragma unroll
            for (int i = 0; i < 16; ++i) part += ch[i] * ep[i];
          }
        }
        redL[t] = part;
      }
      __syncthreads();
      float sv = 0.f;
      if (t < 64) {
        const float b0 = (b == 0) ? bacc[t] : accfin[b * 64 + t];
        sv = b0 - (redL[t * 4] + redL[t * 4 + 1] + redL[t * 4 + 2] + redL[t * 4 + 3]);
      }
      __syncthreads();
      if (t < 64) {                       // wave0: serial diagonal chain
        const float il2 = invLam[b * 64 + t];
        float s = sv, mye = 0.f;
        for (int j = 0; j < 64; ++j) {
          const float xarg = s * il2;
          float e2; asm("v_exp_f32 %0, %1" : "=v"(e2) : "v"(xarg));
          const float den = e2 + 1.f;
          float rc; asm("v_rcp_f32 %0, %1" : "=v"(rc) : "v"(den));
          const float cand = 1.f - 2.f * rc;
          const float ej = __int_as_float(
              __builtin_amdgcn_readlane(__float_as_int(cand), j));
          if (t == j) mye = ej;
          s -= diagL[cur][t * 65 + j] * ej;
        }
        epsR[b & 3][t] = mye;
        eps_g[b * 64 + t] = mye;
      } else if (b < 31) {                // waves1-3: prefetch tiles for b+1
        const int nb = b + 1;
        const int tid2 = t - 64;
        for (int idx = tid2; idx < 1024; idx += 192) {
          const int row = idx >> 4, c4 = (idx & 15) * 4;
          *(float4*)&diagL[nxt][row * 65 + c4] =
              *(const float4*)(H22 + (size_t)(nb * 64 + row) * 2048 + nb * 64 + c4);
        }
#pragma unroll
        for (int sl = 0; sl < 3; ++sl) {
          const int j = nb - 3 + sl;
          if (j >= 0) {
            for (int idx = tid2; idx < 1024; idx += 192) {
              const int row = idx >> 4, c4 = (idx & 15) * 4;
              *(float4*)&chunkL[nxt][sl][row * 68 + c4] =
                  *(const float4*)(H22 + (size_t)(nb * 64 + row) * 2048 + j * 64 + c4);
            }
          }
        }
      }
      __threadfence();
      __syncthreads();
      if (t == 0)
        __hip_atomic_store(&flags[0], (unsigned)(b + 1), __ATOMIC_RELEASE,
                           __HIP_MEMORY_SCOPE_AGENT);
    }
  } else {
    const int r = g;                      // 1..31, covers j <= r-4
    __shared__ float redC[256];
    const int lr = t & 63, q = t >> 6;
    const int grow = r * 64 + lr;
    const float* hrow = H22 + (size_t)grow * 2048;
    float part = 0.f;
    for (int j = 0; j < r - 3; ++j) {
      const float* hp = hrow + j * 64 + q * 16;
      const float4 h0 = *(const float4*)(hp);
      const float4 h1 = *(const float4*)(hp + 4);
      const float4 h2 = *(const float4*)(hp + 8);
      const float4 h3 = *(const float4*)(hp + 12);
      while (__hip_atomic_load(&flags[0], __ATOMIC_ACQUIRE,
                               __HIP_MEMORY_SCOPE_AGENT) < (unsigned)(j + 1))
        __builtin_amdgcn_s_sleep(1);
      const float* ep = eps_g + j * 64 + q * 16;
      const float4 e0 = *(const float4*)(ep);
      const float4 e1 = *(const float4*)(ep + 4);
      const float4 e2 = *(const float4*)(ep + 8);
      const float4 e3 = *(const float4*)(ep + 12);
      part -= h0.x * e0.x + h0.y * e0.y + h0.z * e0.z + h0.w * e0.w
            + h1.x * e1.x + h1.y * e1.y + h1.z * e1.z + h1.w * e1.w
            + h2.x * e2.x + h2.y * e2.y + h2.z * e2.z + h2.w * e2.w
            + h3.x * e3.x + h3.y * e3.y + h3.z * e3.z + h3.w * e3.w;
    }
    redC[q * 64 + lr] = part;
    __syncthreads();
    if (t < 64)
      accfin[r * 64 + t] = bacc[r * 64 + t] + redC[t] + redC[64 + t] +
                           redC[128 + t] + redC[192 + t];
    __threadfence();
    __syncthreads();
    if (t == 0)
      __hip_atomic_store(&flags[64 + r * 16], 1u, __ATOMIC_RELEASE,
                         __HIP_MEMORY_SCOPE_AGENT);
  }
}

// ---------- 5) persistent solver + fused output epilogue ----------
__global__ __launch_bounds__(256) void k_solve(const float* __restrict__ E,
                                               const float* __restrict__ H31,
                                               const float* __restrict__ H32,
                                               const float* __restrict__ B2,
                                               const float* __restrict__ xi,
                                               const float* __restrict__ eps_g,
                                               const float* __restrict__ w,
                                               const float* __restrict__ C2,
                                               const float* __restrict__ D21,
                                               const float* __restrict__ D22,
                                               const float* __restrict__ bu,
                                               float* __restrict__ xv,
                                               float* __restrict__ rbuf,
                                               float* __restrict__ dbuf,
                                               float* __restrict__ out,
                                               unsigned* __restrict__ cnt,
                                               Coefs cf) {
  __shared__ float dn[NXI];
  const int g = blockIdx.x, t = threadIdx.x;
  const int lane = t & 63, wv = t >> 6;
  // r0 = H31@xi + H32@eps + B2@w  (16 rows per block)
#pragma unroll
  for (int rr = 0; rr < 4; ++rr) {
    const int row = g * 16 + wv * 4 + rr;
    const float* fr = H31 + (size_t)row * NXI;
    const float* br = H32 + (size_t)row * NXI;
    float s = 0.f;
    for (int k0 = 0; k0 < NXI; k0 += 256) {
      const int li = k0 + lane * 4;
      const float4 a = *(const float4*)(fr + li);
      const float4 x4 = *(const float4*)(xi + li);
      const float4 b = *(const float4*)(br + li);
      const float4 e4 = *(const float4*)(eps_g + li);
      s += a.x * x4.x + a.y * x4.y + a.z * x4.z + a.w * x4.w
         + b.x * e4.x + b.y * e4.y + b.z * e4.z + b.w * e4.w;
    }
    const float* b2r = B2 + (size_t)row * NN;
    for (int k0 = 0; k0 < NN; k0 += 256) {
      const int li = k0 + lane * 4;
      const float4 a = *(const float4*)(b2r + li);
      const float4 w4 = *(const float4*)(w + li);
      s += a.x * w4.x + a.y * w4.y + a.z * w4.z + a.w * w4.w;
    }
#pragma unroll
    for (int off = 32; off > 0; off >>= 1) s += __shfl_xor(s, off, 64);
    if (lane == 0) rbuf[row] = s;
  }
  gridbar(cnt, 128u);
  for (int i = 0; i < NCHEB; ++i) {
    const float* rin = rbuf + (i & 1) * NXI;
    float* rout = rbuf + ((i + 1) & 1) * NXI;
    const float* din = dbuf + (i & 1) * NXI;
    float* dout = dbuf + ((i + 1) & 1) * NXI;
    const float a1 = cf.g1[i], a2 = cf.g2[i];
    for (int j = t; j < NXI; j += 256) dn[j] = a1 * din[j] + a2 * rin[j];
    __syncthreads();
#pragma unroll
    for (int rr = 0; rr < 4; ++rr) {
      const int row = g * 16 + wv * 4 + rr;
      const float* er = E + (size_t)row * NXI;
      float s = 0.f;
      for (int k0 = 0; k0 < NXI; k0 += 256) {
        const int li = k0 + lane * 4;
        const float4 ev = *(const float4*)(er + li);
        s += ev.x * dn[li] + ev.y * dn[li + 1] + ev.z * dn[li + 2] + ev.w * dn[li + 3];
      }
#pragma unroll
      for (int off = 32; off > 0; off >>= 1) s += __shfl_xor(s, off, 64);
      if (lane == 0) {
        xv[row] += dn[row];
        rout[row] = rin[row] - s;
        dout[row] = dn[row];
      }
    }
    gridbar(cnt, (unsigned)((i + 2) * 128));
  }
  // fused output: xi_next copy + u GEMV (8 rows/block)
  if (t < 16) out[MM + g * 16 + t] = xv[g * 16 + t];
#pragma unroll
  for (int rr = 0; rr < 2; ++rr) {
    const int row = g * 8 + wv * 2 + rr;
    const float* c2r = C2 + (size_t)row * NXI;
    const float* d21r = D21 + (size_t)row * LLEN;
    const float* d22r = D22 + (size_t)row * NN;
    float s = 0.f;
    for (int k0 = 0; k0 < NXI; k0 += 256) {
      const int li = k0 + lane * 4;
      const float4 a = *(const float4*)(c2r + li);
      const float4 xvv = *(const float4*)(xi + li);
      const float4 b = *(const float4*)(d21r + li);
      const float4 ev = *(const float4*)(eps_g + li);
      s += a.x * xvv.x + a.y * xvv.y + a.z * xvv.z + a.w * xvv.w
         + b.x * ev.x + b.y * ev.y + b.z * ev.z + b.w * ev.w;
    }
    for (int k0 = 0; k0 < NN; k0 += 256) {
      const int li = k0 + lane * 4;
      const float4 a = *(const float4*)(d22r + li);
      const float4 w4 = *(const float4*)(w + li);
      s += a.x * w4.x + a.y * w4.y + a.z * w4.z + a.w * w4.w;
    }
#pragma unroll
    for (int off = 32; off > 0; off >>= 1) s += __shfl_xor(s, off, 64);
    if (lane == 0) {
      const float u = s + bu[row];
      const float sg = 1.f / (1.f + __expf(-u));
      out[row] = 8.0f + 4.8f * sg;
    }
  }
}

// ---------- launch ----------
extern "C" void kernel_launch(void* const* d_in, const int* in_sizes, int n_in,
                              void* d_out, int out_size, void* d_ws, size_t ws_size,
                              hipStream_t stream) {
  (void)in_sizes; (void)n_in; (void)out_size;
  const float* w   = (const float*)d_in[1];
  const float* xi  = (const float*)d_in[2];
  const float* X   = (const float*)d_in[3];
  const float* Y   = (const float*)d_in[4];
  const float* B2  = (const float*)d_in[5];
  const float* C2  = (const float*)d_in[6];
  const float* D21 = (const float*)d_in[7];
  const float* D22 = (const float*)d_in[8];
  const float* D12 = (const float*)d_in[9];
  const float* bu  = (const float*)d_in[10];
  float* out = (float*)d_out;

  char* ws = (char*)d_ws;
  ushort_t* XT = (ushort_t*)ws;                                   // 75,497,472 B
  float* Enew  = (float*)ws;                                      // reuses XT after k_syrk
  float* H = (float*)(ws + 75497472ull);                          // 100,663,296 B
  float* vecs = (float*)(ws + 75497472ull + 100663296ull);
  float* invLam = vecs;              // 2048
  float* bacc   = vecs + 2048;
  float* accfin = vecs + 4096;
  float* eps_g  = vecs + 6144;
  float* xv     = vecs + 8192;
  float* rbuf   = vecs + 10240;      // 2 x 2048
  float* dbuf   = vecs + 14336;      // 2 x 2048
  unsigned* flags = (unsigned*)(vecs + 18432);   // 8 KB zeroed
  unsigned* cnt   = flags + 1024;

  float* H11 = H;
  float* H21 = H + 1ull * 2048 * 2048;
  float* H22 = H + 2ull * 2048 * 2048;
  float* H31 = H + 3ull * 2048 * 2048;
  float* H32 = H + 4ull * 2048 * 2048;
  float* H33 = H + 5ull * 2048 * 2048;

  hipMemsetAsync(flags, 0, 8192, stream);
  hipMemsetAsync(xv, 0, 2048 * sizeof(float), stream);
  // zero the K-split tail region: z4 rows 1792..2047 (2 MB) + all of z5 (16 MB), contiguous
  hipMemsetAsync((char*)H + 81788928ull, 0, 18874368ull, stream);

  k_transpose<<<dim3(96, 96), 256, 0, stream>>>(X, XT);
  k_syrk<<<432, 512, 0, stream>>>(XT, H);
  k_mid<<<1160, 256, 0, stream>>>(H11, H33, Y, Enew, H22, invLam, H21, D12, xi, w, bacc);
  k_eps<<<32, 256, 0, stream>>>(H22, bacc, invLam, eps_g, accfin, flags);

  // Chebyshev coefficients on [16, 130] (Re-spectrum of E ~ [21.5, 121.8])
  Coefs cf;
  {
    const double lmin = 16.0, lmax = 130.0;
    const double theta = 0.5 * (lmax + lmin), delta = 0.5 * (lmax - lmin);
    const double sigma1 = theta / delta;
    double rho_prev = delta / theta;
    for (int i = 0; i < NCHEB; ++i) {
      if (i == 0) { cf.g1[0] = 0.f; cf.g2[0] = (float)(1.0 / theta); }
      else {
        const double rho = 1.0 / (2.0 * sigma1 - rho_prev);
        cf.g1[i] = (float)(rho * rho_prev);
        cf.g2[i] = (float)(2.0 * rho / delta);
        rho_prev = rho;
      }
    }
  }
  k_solve<<<128, 256, 0, stream>>>(Enew, H31, H32, B2, xi, eps_g, w,
                                   C2, D21, D22, bu, xv, rbuf, dbuf, out, cnt, cf);
}